// Round 7
// baseline (121.392 us; speedup 1.0000x reference)
//
#include <hip/hip_runtime.h>
#include <math.h>

#define NA 5
#define NC 20
#define NH 38
#define NW 38
#define MAX_BOXES 50
#define SPAT (NH * NW)            // 1444
#define CELLS_PER_B (NA * SPAT)   // 7220
#define TPB 256                   // 4 waves per WG (barrier-free until final combine)
#define WAVES 4
#define CPT 4                     // cells per thread (float4 loads)
#define CPW (64 * CPT)            // 256 cells per wave-slab
#define SLABS ((CELLS_PER_B + CPW - 1) / CPW)  // 29
#define GXB 8                     // WG0: prep + 3 slabs; WG1..7: 4 slabs (3+28=31 >= 29)
#define OBJECT_SCALE 5.0f
#define NOOBJECT_SCALE 1.0f

__constant__ float c_aw[NA]  = {1.3221f, 3.19275f, 5.05587f, 9.47112f, 11.2364f};
__constant__ float c_ah[NA]  = {1.73145f, 4.00944f, 8.09892f, 4.84053f, 10.0071f};
__constant__ float c_iaw[NA] = {1.f/1.3221f, 1.f/3.19275f, 1.f/5.05587f, 1.f/9.47112f, 1.f/11.2364f};
__constant__ float c_iah[NA] = {1.f/1.73145f, 1.f/4.00944f, 1.f/8.09892f, 1.f/4.84053f, 1.f/10.0071f};

// Completion counter for the last-WG-done final reduction.
// Lives in module .data (NOT the re-poisoned workspace); the last WG resets it
// to 0 each launch, so the invariant holds across graph replays with no API calls.
__device__ int g_counter = 0;

__device__ __forceinline__ float fexp(float v) { return __expf(v); }
__device__ __forceinline__ float flog(float v) { return __logf(v); }
__device__ __forceinline__ float frcp(float v) { return __builtin_amdgcn_rcpf(v); }
__device__ __forceinline__ float fsig(float v) { return frcp(1.f + __expf(-v)); }

// within-wave LDS write->read ordering: HW wait + compiler reorder fence.
// (each wave touches ONLY its own LDS slice in the main phase)
__device__ __forceinline__ void wave_lds_fence() {
  asm volatile("s_waitcnt lgkmcnt(0)" ::: "memory");
}

__device__ __forceinline__ float iou_fast(float x1, float y1, float w1, float h1,
                                          float x2, float y2, float w2, float h2) {
  float uw = fmaxf(x1 + w1 * 0.5f, x2 + w2 * 0.5f) - fminf(x1 - w1 * 0.5f, x2 - w2 * 0.5f);
  float uh = fmaxf(y1 + h1 * 0.5f, y2 + h2 * 0.5f) - fminf(y1 - h1 * 0.5f, y2 - h2 * 0.5f);
  float cw = w1 + w2 - uw;
  float ch = h1 + h2 - uh;
  float inter = (cw <= 0.f || ch <= 0.f) ? 0.f : cw * ch;
  return inter * frcp(w1 * h1 + w2 * h2 - inter);
}

// exact divide for the anchor argmax (discrete decision -> keep exact)
__device__ __forceinline__ float iou_wh_exact(float w1, float h1, float w2, float h2) {
  float uw = fmaxf(w1 * 0.5f, w2 * 0.5f) - fminf(-w1 * 0.5f, -w2 * 0.5f);
  float uh = fmaxf(h1 * 0.5f, h2 * 0.5f) - fminf(-h1 * 0.5f, -h2 * 0.5f);
  float cw = w1 + w2 - uw;
  float ch = h1 + h2 - uh;
  float inter = (cw <= 0.f || ch <= 0.f) ? 0.f : cw * ch;
  return inter / (w1 * h1 + w2 * h2 - inter);
}

// ---------- Single fused kernel. Grid (GXB, nB), 256 threads = 4 waves. ----------
// Waves are independent until the end-of-kernel combine:
//   block x==0, wave 0 : winner-delta (prep) wave for batch b
//   block x==0, waves 1-3 : main slabs 0..2
//   block x>=1, wave w : main slab 3 + (x-1)*4 + w   (idle past SLABS-1)
// Box rebuild is textually identical in prep and main waves, preserving the
// exact W-D cancellation (absmax 0.0 through rounds 0/1/4/5/6).
// Epilogue: per-WG partial -> threadfence -> atomicAdd(g_counter); the unique
// last WG gathers all WG-partials in a FIXED order (deterministic), writes
// d_out, and resets g_counter (no reduce kernel, no counter-init memset).
__global__ __launch_bounds__(TPB) void fused_kernel(
    const float* __restrict__ out, const float* __restrict__ target,
    float* __restrict__ partials, float* __restrict__ outv, int total) {
  const int b = blockIdx.y;
  const int wid = threadIdx.x >> 6;
  const int lane = threadIdx.x & 63;

  __shared__ float4 sb_lo[WAVES][MAX_BOXES];
  __shared__ float  sb_ag[WAVES][MAX_BOXES];
  __shared__ float  s_red[WAVES];

  float wacc = 0.f;   // this wave's partial

  if (blockIdx.x == 0 && wid == 0) {
    // ---------------- prep wave: winner deltas only ----------------
    const int t = lane;
    float cls = 0.f, x = 0.f, y = 0.f, w = 0.f, h = 0.f;
    if (t < MAX_BOXES) {
      const float* tg = target + (size_t)(b * MAX_BOXES + t) * 5;
      cls = tg[0]; x = tg[1]; y = tg[2]; w = tg[3]; h = tg[4];
    }
    unsigned long long nz = __ballot(t < MAX_BOXES && x != 0.f);
    unsigned long long low = (t < 63) ? ((1ull << (t + 1)) - 1ull) : ~0ull;
    bool valid = (t < MAX_BOXES) && ((nz & low) == low);
    float gx = x * NW, gy = y * NH, gw = w * NW, gh = h * NH;

    int best = 0; float bestiou = -1.f;
#pragma unroll
    for (int a2 = 0; a2 < NA; ++a2) {
      float aiou = iou_wh_exact(gw, gh, c_aw[a2], c_ah[a2]);
      if (aiou > bestiou) { bestiou = aiou; best = a2; }
    }
    int gi = min(max((int)gx, 0), NW - 1);
    int gj = min(max((int)gy, 0), NH - 1);
    int cell = best * SPAT + gj * NW + gi;

    unsigned long long vm = __ballot(valid);
    bool winner = valid;                       // last valid writer to a cell wins
    for (int tp = 0; tp < MAX_BOXES; ++tp) {
      int c2 = __shfl(cell, tp);
      if (tp > t && ((vm >> tp) & 1ull) && c2 == cell) winner = false;
    }
    if (t < MAX_BOXES) {
      if (valid) {
        sb_lo[0][t] = make_float4(gx - gw * 0.5f, gx + gw * 0.5f, gy - gh * 0.5f, gy + gh * 0.5f);
        sb_ag[0][t] = 0.375f * (gw * gh);
      } else {
        sb_lo[0][t] = make_float4(1e30f, 1e30f, 1e30f, 1e30f);  // never suppresses
        sb_ag[0][t] = 0.f;
      }
    }
    wave_lds_fence();

    float d = 0.f;
    if (winner) {
      const float* bp = out + ((size_t)(b * NA + best) * 25) * SPAT + gj * NW + gi;
      float v0 = bp[0], v1 = bp[SPAT], v2 = bp[2 * SPAT], v3 = bp[3 * SPAT], v4 = bp[4 * SPAT];
      float xs = fsig(v0), ys = fsig(v1), cs = fsig(v4);
      float pw = fexp(v2) * c_aw[best], ph = fexp(v3) * c_ah[best];
      float px = xs + (float)gi, py = ys + (float)gj;
      float plx = px - pw * 0.5f, phx = px + pw * 0.5f;
      float ply = py - ph * 0.5f, phy = py + ph * 0.5f;
      float ap = 0.375f * (pw * ph);

      // replicate the main path's default term at this cell (textually identical)
      float msc = -1e30f;
      for (int t2 = 0; t2 < MAX_BOXES; ++t2) {
        float4 l2 = sb_lo[0][t2];
        float cw = fminf(phx, l2.y) - fmaxf(plx, l2.x);
        float ch = fminf(phy, l2.w) - fmaxf(ply, l2.z);
        cw = fmaxf(cw, 0.f);
        msc = fmaxf(msc, fmaf(cw, ch, -sb_ag[0][t2]));
      }
      float cmask_def = (msc > ap) ? 0.f : NOOBJECT_SCALE;
      float xd = xs - 0.5f, yd = ys - 0.5f;
      float D = 0.5f * (xd * xd + yd * yd + v2 * v2 + v3 * v3 + cmask_def * (cs * cs));

      // winner terms
      float txv = gx - (float)gi, tyv = gy - (float)gj;
      float twv = flog(gw * c_iaw[best]), thv = flog(gh * c_iah[best]);
      float tconf = iou_fast(gx, gy, gw, gh, px, py, pw, ph);
      float dx = xs - txv, dy = ys - tyv, dwv = v2 - twv, dhv = v3 - thv, dc = cs - tconf;

      // class CE: TWO-PASS (register-lean; reloads are L1/L2-hot, bit-identical)
      int label = (int)cls;
      const float* cb = bp + 5 * SPAT;
      float m = -1e30f, lv = 0.f;
      for (int c = 0; c < NC; ++c) {
        float vvc = cb[c * SPAT];
        if (c == label) lv = vvc;
        m = fmaxf(m, vvc);
      }
      float ssum = 0.f;
      for (int c = 0; c < NC; ++c) ssum += fexp(cb[c * SPAT] - m);
      float ce = (m + flog(ssum)) - lv;       // -log_softmax[label]

      float W = 0.5f * (dx * dx + dy * dy + dwv * dwv + dhv * dhv +
                        OBJECT_SCALE * (dc * dc)) + ce;
      d = W - D;
    }
    for (int o = 32; o > 0; o >>= 1) d += __shfl_down(d, o, 64);
    wacc = d;   // lane 0 holds the prep partial
  } else {
    // ---------------- main wave: 256 cells (4/thread), fully regular ----------------
    const int slab = (blockIdx.x == 0) ? (wid - 1) : (3 + (blockIdx.x - 1) * WAVES + wid);
    const int s0 = slab * CPW + lane * CPT;           // first of 4 consecutive cells
    // clamp base in-bounds (7220-4=7216, 4-aligned); 1444%4==0 so an aligned
    // float4 never crosses an anchor boundary. Clamped threads masked below.
    const int sbase = (s0 < CELLS_PER_B - CPT) ? s0 : (CELLS_PER_B - CPT);
    const bool live = (slab < SLABS);
    unsigned a = (unsigned)sbase / SPAT;
    unsigned r0 = (unsigned)sbase - a * SPAT;
    const float paw = c_aw[a], pah = c_ah[a];

    float4 q0 = make_float4(0.f, 0.f, 0.f, 0.f), q1 = q0, q2 = q0, q3 = q0, q4 = q0;
    if (live) {
      const float* bp = out + ((size_t)(b * NA + a) * 25) * SPAT + r0;
      q0 = *(const float4*)(bp);
      q1 = *(const float4*)(bp + SPAT);
      q2 = *(const float4*)(bp + 2 * SPAT);
      q3 = *(const float4*)(bp + 3 * SPAT);
      q4 = *(const float4*)(bp + 4 * SPAT);
    }

    // this wave rebuilds the 50 suppression boxes into ITS OWN LDS slice
    {
      float x = 0.f, y = 0.f, w = 0.f, h = 0.f;
      if (lane < MAX_BOXES) {
        const float* tg = target + (size_t)(b * MAX_BOXES + lane) * 5;
        x = tg[1]; y = tg[2]; w = tg[3]; h = tg[4];
      }
      unsigned long long nz = __ballot(lane < MAX_BOXES && x != 0.f);
      unsigned long long low = (lane < 63) ? ((1ull << (lane + 1)) - 1ull) : ~0ull;
      bool valid = (lane < MAX_BOXES) && ((nz & low) == low);
      float gx = x * NW, gy = y * NH, gw = w * NW, gh = h * NH;
      if (lane < MAX_BOXES) {
        if (valid) {
          sb_lo[wid][lane] = make_float4(gx - gw * 0.5f, gx + gw * 0.5f, gy - gh * 0.5f, gy + gh * 0.5f);
          sb_ag[wid][lane] = 0.375f * (gw * gh);
        } else {
          sb_lo[wid][lane] = make_float4(1e30f, 1e30f, 1e30f, 1e30f);
          sb_ag[wid][lane] = 0.f;
        }
      }
    }

    // per-cell transcendental math (independent of LDS), textually identical per cell
    float v0[CPT] = {q0.x, q0.y, q0.z, q0.w};
    float v1[CPT] = {q1.x, q1.y, q1.z, q1.w};
    float v2[CPT] = {q2.x, q2.y, q2.z, q2.w};
    float v3[CPT] = {q3.x, q3.y, q3.z, q3.w};
    float v4[CPT] = {q4.x, q4.y, q4.z, q4.w};
    float xs[CPT], ys[CPT], cs[CPT];
    float plx[CPT], phx[CPT], ply[CPT], phy[CPT], ap[CPT], msc[CPT];
#pragma unroll
    for (int q = 0; q < CPT; ++q) {
      unsigned r = r0 + q;                 // r0+3 <= 1443 (aligned, no boundary cross)
      unsigned j = r / NW, i = r - j * NW;
      float fi = (float)i, fj = (float)j;
      xs[q] = fsig(v0[q]);
      ys[q] = fsig(v1[q]);
      cs[q] = fsig(v4[q]);
      float pw = fexp(v2[q]) * paw, ph = fexp(v3[q]) * pah;
      float px = xs[q] + fi, py = ys[q] + fj;
      plx[q] = px - pw * 0.5f; phx[q] = px + pw * 0.5f;
      ply[q] = py - ph * 0.5f; phy[q] = py + ph * 0.5f;
      ap[q] = 0.375f * (pw * ph);
      msc[q] = -1e30f;
    }
    wave_lds_fence();   // own-slice write->read ordering; no cross-wave coupling

    // suppression: max_iou>0.6  <=>  max_t( max(cw,0)*ch - 0.375*Ag_t ) > 0.375*Ap
#pragma unroll
    for (int c0 = 0; c0 < MAX_BOXES; c0 += 5) {
      float4 bl[5]; float bag[5];
#pragma unroll
      for (int u = 0; u < 5; ++u) { bl[u] = sb_lo[wid][c0 + u]; bag[u] = sb_ag[wid][c0 + u]; }
#pragma unroll
      for (int u = 0; u < 5; ++u) {
#pragma unroll
        for (int q = 0; q < CPT; ++q) {
          float cw = fminf(phx[q], bl[u].y) - fmaxf(plx[q], bl[u].x);
          float ch = fminf(phy[q], bl[u].w) - fmaxf(ply[q], bl[u].z);
          cw = fmaxf(cw, 0.f);
          msc[q] = fmaxf(msc[q], fmaf(cw, ch, -bag[u]));
        }
      }
    }

    float acc = 0.f;
#pragma unroll
    for (int q = 0; q < CPT; ++q) {
      // clamped threads (sbase != s0) have all true cells out of range
      bool okq = live && (s0 + q < CELLS_PER_B) && (s0 == sbase);
      if (!okq) continue;
      float cmask = (msc[q] > ap[q]) ? 0.f : NOOBJECT_SCALE;
      float xd = xs[q] - 0.5f, yd = ys[q] - 0.5f;
      acc += 0.5f * (xd * xd + yd * yd + v2[q] * v2[q] + v3[q] * v3[q] +
                     cmask * (cs[q] * cs[q]));
    }
    for (int o = 32; o > 0; o >>= 1) acc += __shfl_down(acc, o, 64);
    wacc = acc;
  }

  // ---------------- WG combine + last-WG final reduction ----------------
  if (lane == 0) s_red[wid] = wacc;
  __syncthreads();                 // end-of-kernel: all waves done anyway

  if (wid == 0) {
    float wg = 0.f;
    if (lane == 0) {
      wg = s_red[0] + s_red[1] + s_red[2] + s_red[3];   // fixed order
      partials[(size_t)b * GXB + blockIdx.x] = wg;
    }
    __threadfence();               // device-scope release (cross-XCD visible)
    int old = 0;
    if (lane == 0) old = atomicAdd(&g_counter, 1);
    old = __shfl(old, 0, 64);
    if (old == total - 1) {        // unique last WG
      __threadfence();             // acquire: see all partials
      float acc = 0.f;
      for (int i2 = lane; i2 < total; i2 += 64) acc += partials[i2];  // fixed order
      for (int o = 32; o > 0; o >>= 1) acc += __shfl_down(acc, o, 64);
      if (lane == 0) {
        outv[0] = acc;
        atomicExch(&g_counter, 0); // reset for the next launch/replay
      }
    }
  }
}

extern "C" void kernel_launch(void* const* d_in, const int* in_sizes, int n_in,
                              void* d_out, int out_size, void* d_ws, size_t ws_size,
                              hipStream_t stream) {
  const float* out = (const float*)d_in[0];
  const float* target = (const float*)d_in[1];
  int nB = in_sizes[0] / (NA * (5 + NC) * SPAT);

  float* partials = (float*)d_ws;   // GXB*nB floats

  hipLaunchKernelGGL(fused_kernel, dim3(GXB, nB), dim3(TPB), 0, stream,
                     out, target, partials, (float*)d_out, GXB * nB);
}

// Round 8
// 99.268 us; speedup vs baseline: 1.2229x; 1.2229x over previous
//
#include <hip/hip_runtime.h>
#include <math.h>

#define NA 5
#define NC 20
#define NH 38
#define NW 38
#define MAX_BOXES 50
#define SPAT (NH * NW)            // 1444
#define CELLS_PER_B (NA * SPAT)   // 7220
#define TPB 256                   // 4 independent waves per WG (barrier-free)
#define WAVES 4
#define CPT 4                     // cells per thread (float4 loads)
#define CPW (64 * CPT)            // 256 cells per wave-slab
#define SLABS ((CELLS_PER_B + CPW - 1) / CPW)  // 29
#define GXB 8                     // WG0: prep + 3 slabs; WG1..7: 4 slabs (3+28=31 >= 29)
#define WTOT (GXB * WAVES)        // 32 partials per batch
#define OBJECT_SCALE 5.0f
#define NOOBJECT_SCALE 1.0f

__constant__ float c_aw[NA]  = {1.3221f, 3.19275f, 5.05587f, 9.47112f, 11.2364f};
__constant__ float c_ah[NA]  = {1.73145f, 4.00944f, 8.09892f, 4.84053f, 10.0071f};
__constant__ float c_iaw[NA] = {1.f/1.3221f, 1.f/3.19275f, 1.f/5.05587f, 1.f/9.47112f, 1.f/11.2364f};
__constant__ float c_iah[NA] = {1.f/1.73145f, 1.f/4.00944f, 1.f/8.09892f, 1.f/4.84053f, 1.f/10.0071f};

__device__ __forceinline__ float fexp(float v) { return __expf(v); }
__device__ __forceinline__ float flog(float v) { return __logf(v); }
__device__ __forceinline__ float frcp(float v) { return __builtin_amdgcn_rcpf(v); }
__device__ __forceinline__ float fsig(float v) { return frcp(1.f + __expf(-v)); }

// within-wave LDS write->read ordering: HW wait + compiler reorder fence.
// (each wave touches ONLY its own LDS slice, so wave scope is sufficient)
__device__ __forceinline__ void wave_lds_fence() {
  asm volatile("s_waitcnt lgkmcnt(0)" ::: "memory");
}

__device__ __forceinline__ float iou_fast(float x1, float y1, float w1, float h1,
                                          float x2, float y2, float w2, float h2) {
  float uw = fmaxf(x1 + w1 * 0.5f, x2 + w2 * 0.5f) - fminf(x1 - w1 * 0.5f, x2 - w2 * 0.5f);
  float uh = fmaxf(y1 + h1 * 0.5f, y2 + h2 * 0.5f) - fminf(y1 - h1 * 0.5f, y2 - h2 * 0.5f);
  float cw = w1 + w2 - uw;
  float ch = h1 + h2 - uh;
  float inter = (cw <= 0.f || ch <= 0.f) ? 0.f : cw * ch;
  return inter * frcp(w1 * h1 + w2 * h2 - inter);
}

// exact divide for the anchor argmax (discrete decision -> keep exact)
__device__ __forceinline__ float iou_wh_exact(float w1, float h1, float w2, float h2) {
  float uw = fmaxf(w1 * 0.5f, w2 * 0.5f) - fminf(-w1 * 0.5f, -w2 * 0.5f);
  float uh = fmaxf(h1 * 0.5f, h2 * 0.5f) - fminf(-h1 * 0.5f, -h2 * 0.5f);
  float cw = w1 + w2 - uw;
  float ch = h1 + h2 - uh;
  float inter = (cw <= 0.f || ch <= 0.f) ? 0.f : cw * ch;
  return inter / (w1 * h1 + w2 * h2 - inter);
}

// ---------- Fused kernel. Grid (GXB, nB), 256 threads = 4 independent waves. ----------
// Barrier-free: each wave owns a private LDS slice and rebuilds the 50 boxes
// itself with textually identical arithmetic (exact W-D cancellation preserved;
// absmax 0.0 through rounds 0/1/4/5/6).
//   block x==0, wave 0 : winner-delta (prep) wave for batch b
//   block x==0, waves 1-3 : main slabs 0..2
//   block x>=1, wave w : main slab 3 + (x-1)*4 + w   (idle past SLABS-1)
// Main wave = 256 cells: 4 cells/thread via 5x global_load_dwordx4 (16B/lane).
// NOTE (r7 post-mortem): do NOT fuse the final reduction into this kernel --
// the device-scope __threadfence + single-counter protocol cost +22 us
// (L2-writeback storm from 512 WGs). Two kernels is the cheaper structure.
__global__ __launch_bounds__(TPB) void fused_kernel(
    const float* __restrict__ out, const float* __restrict__ target,
    float* __restrict__ partials) {
  const int b = blockIdx.y;
  const int wid = threadIdx.x >> 6;
  const int lane = threadIdx.x & 63;

  __shared__ float4 sb_lo[WAVES][MAX_BOXES];
  __shared__ float  sb_ag[WAVES][MAX_BOXES];

  if (blockIdx.x == 0 && wid == 0) {
    // ---------------- prep wave: winner deltas only ----------------
    const int t = lane;
    float cls = 0.f, x = 0.f, y = 0.f, w = 0.f, h = 0.f;
    if (t < MAX_BOXES) {
      const float* tg = target + (size_t)(b * MAX_BOXES + t) * 5;
      cls = tg[0]; x = tg[1]; y = tg[2]; w = tg[3]; h = tg[4];
    }
    unsigned long long nz = __ballot(t < MAX_BOXES && x != 0.f);
    unsigned long long low = (t < 63) ? ((1ull << (t + 1)) - 1ull) : ~0ull;
    bool valid = (t < MAX_BOXES) && ((nz & low) == low);
    float gx = x * NW, gy = y * NH, gw = w * NW, gh = h * NH;

    int best = 0; float bestiou = -1.f;
#pragma unroll
    for (int a2 = 0; a2 < NA; ++a2) {
      float aiou = iou_wh_exact(gw, gh, c_aw[a2], c_ah[a2]);
      if (aiou > bestiou) { bestiou = aiou; best = a2; }
    }
    int gi = min(max((int)gx, 0), NW - 1);
    int gj = min(max((int)gy, 0), NH - 1);
    int cell = best * SPAT + gj * NW + gi;

    unsigned long long vm = __ballot(valid);
    bool winner = valid;                       // last valid writer to a cell wins
    for (int tp = 0; tp < MAX_BOXES; ++tp) {
      int c2 = __shfl(cell, tp);
      if (tp > t && ((vm >> tp) & 1ull) && c2 == cell) winner = false;
    }
    if (t < MAX_BOXES) {
      if (valid) {
        sb_lo[0][t] = make_float4(gx - gw * 0.5f, gx + gw * 0.5f, gy - gh * 0.5f, gy + gh * 0.5f);
        sb_ag[0][t] = 0.375f * (gw * gh);
      } else {
        sb_lo[0][t] = make_float4(1e30f, 1e30f, 1e30f, 1e30f);  // never suppresses
        sb_ag[0][t] = 0.f;
      }
    }
    wave_lds_fence();

    float d = 0.f;
    if (winner) {
      const float* bp = out + ((size_t)(b * NA + best) * 25) * SPAT + gj * NW + gi;
      float v0 = bp[0], v1 = bp[SPAT], v2 = bp[2 * SPAT], v3 = bp[3 * SPAT], v4 = bp[4 * SPAT];
      float xs = fsig(v0), ys = fsig(v1), cs = fsig(v4);
      float pw = fexp(v2) * c_aw[best], ph = fexp(v3) * c_ah[best];
      float px = xs + (float)gi, py = ys + (float)gj;
      float plx = px - pw * 0.5f, phx = px + pw * 0.5f;
      float ply = py - ph * 0.5f, phy = py + ph * 0.5f;
      float ap = 0.375f * (pw * ph);

      // replicate the main path's default term at this cell (textually identical)
      float msc = -1e30f;
      for (int t2 = 0; t2 < MAX_BOXES; ++t2) {
        float4 l2 = sb_lo[0][t2];
        float cw = fminf(phx, l2.y) - fmaxf(plx, l2.x);
        float ch = fminf(phy, l2.w) - fmaxf(ply, l2.z);
        cw = fmaxf(cw, 0.f);
        msc = fmaxf(msc, fmaf(cw, ch, -sb_ag[0][t2]));
      }
      float cmask_def = (msc > ap) ? 0.f : NOOBJECT_SCALE;
      float xd = xs - 0.5f, yd = ys - 0.5f;
      float D = 0.5f * (xd * xd + yd * yd + v2 * v2 + v3 * v3 + cmask_def * (cs * cs));

      // winner terms
      float txv = gx - (float)gi, tyv = gy - (float)gj;
      float twv = flog(gw * c_iaw[best]), thv = flog(gh * c_iah[best]);
      float tconf = iou_fast(gx, gy, gw, gh, px, py, pw, ph);
      float dx = xs - txv, dy = ys - tyv, dwv = v2 - twv, dhv = v3 - thv, dc = cs - tconf;

      // class CE: TWO-PASS (register-lean; reloads are L1/L2-hot, bit-identical)
      int label = (int)cls;
      const float* cb = bp + 5 * SPAT;
      float m = -1e30f, lv = 0.f;
      for (int c = 0; c < NC; ++c) {
        float vvc = cb[c * SPAT];
        if (c == label) lv = vvc;
        m = fmaxf(m, vvc);
      }
      float ssum = 0.f;
      for (int c = 0; c < NC; ++c) ssum += fexp(cb[c * SPAT] - m);
      float ce = (m + flog(ssum)) - lv;       // -log_softmax[label]

      float W = 0.5f * (dx * dx + dy * dy + dwv * dwv + dhv * dhv +
                        OBJECT_SCALE * (dc * dc)) + ce;
      d = W - D;
    }
    for (int o = 32; o > 0; o >>= 1) d += __shfl_down(d, o, 64);
    if (lane == 0) partials[(size_t)b * WTOT] = d;
    return;
  }

  // ---------------- main wave: 256 cells (4/thread), fully regular ----------------
  const int slab = (blockIdx.x == 0) ? (wid - 1) : (3 + (blockIdx.x - 1) * WAVES + wid);
  const int s0 = slab * CPW + lane * CPT;           // first of 4 consecutive cells
  // clamp base in-bounds (7220-4=7216, 4-aligned); 1444%4==0 so an aligned
  // float4 never crosses an anchor boundary. Clamped threads masked below.
  const int sbase = (s0 < CELLS_PER_B - CPT) ? s0 : (CELLS_PER_B - CPT);
  const bool live = (slab < SLABS);
  unsigned a = (unsigned)sbase / SPAT;
  unsigned r0 = (unsigned)sbase - a * SPAT;
  const float paw = c_aw[a], pah = c_ah[a];

  float4 q0 = make_float4(0.f, 0.f, 0.f, 0.f), q1 = q0, q2 = q0, q3 = q0, q4 = q0;
  if (live) {
    const float* bp = out + ((size_t)(b * NA + a) * 25) * SPAT + r0;
    q0 = *(const float4*)(bp);
    q1 = *(const float4*)(bp + SPAT);
    q2 = *(const float4*)(bp + 2 * SPAT);
    q3 = *(const float4*)(bp + 3 * SPAT);
    q4 = *(const float4*)(bp + 4 * SPAT);
  }

  // this wave rebuilds the 50 suppression boxes into ITS OWN LDS slice
  {
    float x = 0.f, y = 0.f, w = 0.f, h = 0.f;
    if (lane < MAX_BOXES) {
      const float* tg = target + (size_t)(b * MAX_BOXES + lane) * 5;
      x = tg[1]; y = tg[2]; w = tg[3]; h = tg[4];
    }
    unsigned long long nz = __ballot(lane < MAX_BOXES && x != 0.f);
    unsigned long long low = (lane < 63) ? ((1ull << (lane + 1)) - 1ull) : ~0ull;
    bool valid = (lane < MAX_BOXES) && ((nz & low) == low);
    float gx = x * NW, gy = y * NH, gw = w * NW, gh = h * NH;
    if (lane < MAX_BOXES) {
      if (valid) {
        sb_lo[wid][lane] = make_float4(gx - gw * 0.5f, gx + gw * 0.5f, gy - gh * 0.5f, gy + gh * 0.5f);
        sb_ag[wid][lane] = 0.375f * (gw * gh);
      } else {
        sb_lo[wid][lane] = make_float4(1e30f, 1e30f, 1e30f, 1e30f);
        sb_ag[wid][lane] = 0.f;
      }
    }
  }

  // per-cell transcendental math (independent of LDS), textually identical per cell
  float v0[CPT] = {q0.x, q0.y, q0.z, q0.w};
  float v1[CPT] = {q1.x, q1.y, q1.z, q1.w};
  float v2[CPT] = {q2.x, q2.y, q2.z, q2.w};
  float v3[CPT] = {q3.x, q3.y, q3.z, q3.w};
  float v4[CPT] = {q4.x, q4.y, q4.z, q4.w};
  float xs[CPT], ys[CPT], cs[CPT];
  float plx[CPT], phx[CPT], ply[CPT], phy[CPT], ap[CPT], msc[CPT];
#pragma unroll
  for (int q = 0; q < CPT; ++q) {
    unsigned r = r0 + q;                 // r0+3 <= 1443 (aligned, no boundary cross)
    unsigned j = r / NW, i = r - j * NW;
    float fi = (float)i, fj = (float)j;
    xs[q] = fsig(v0[q]);
    ys[q] = fsig(v1[q]);
    cs[q] = fsig(v4[q]);
    float pw = fexp(v2[q]) * paw, ph = fexp(v3[q]) * pah;
    float px = xs[q] + fi, py = ys[q] + fj;
    plx[q] = px - pw * 0.5f; phx[q] = px + pw * 0.5f;
    ply[q] = py - ph * 0.5f; phy[q] = py + ph * 0.5f;
    ap[q] = 0.375f * (pw * ph);
    msc[q] = -1e30f;
  }
  wave_lds_fence();   // own-slice write->read ordering; no cross-wave coupling

  // suppression: max_iou>0.6  <=>  max_t( max(cw,0)*ch - 0.375*Ag_t ) > 0.375*Ap
#pragma unroll
  for (int c0 = 0; c0 < MAX_BOXES; c0 += 5) {
    float4 bl[5]; float bag[5];
#pragma unroll
    for (int u = 0; u < 5; ++u) { bl[u] = sb_lo[wid][c0 + u]; bag[u] = sb_ag[wid][c0 + u]; }
#pragma unroll
    for (int u = 0; u < 5; ++u) {
#pragma unroll
      for (int q = 0; q < CPT; ++q) {
        float cw = fminf(phx[q], bl[u].y) - fmaxf(plx[q], bl[u].x);
        float ch = fminf(phy[q], bl[u].w) - fmaxf(ply[q], bl[u].z);
        cw = fmaxf(cw, 0.f);
        msc[q] = fmaxf(msc[q], fmaf(cw, ch, -bag[u]));
      }
    }
  }

  float acc = 0.f;
#pragma unroll
  for (int q = 0; q < CPT; ++q) {
    // clamped threads (sbase != s0) have all true cells out of range
    bool okq = live && (s0 + q < CELLS_PER_B) && (s0 == sbase);
    if (!okq) continue;
    float cmask = (msc[q] > ap[q]) ? 0.f : NOOBJECT_SCALE;
    float xd = xs[q] - 0.5f, yd = ys[q] - 0.5f;
    acc += 0.5f * (xd * xd + yd * yd + v2[q] * v2[q] + v3[q] * v3[q] +
                   cmask * (cs[q] * cs[q]));
  }
  for (int o = 32; o > 0; o >>= 1) acc += __shfl_down(acc, o, 64);
  if (lane == 0) partials[(size_t)b * WTOT + blockIdx.x * WAVES + wid] = acc;
}

// ---------- K2: final reduce over WTOT*nB contiguous partials. ----------
__global__ __launch_bounds__(256) void reduce_kernel(
    const float* __restrict__ vals, int n, float* __restrict__ outv) {
  float acc = 0.f;
  for (int i = threadIdx.x; i < n; i += 256) acc += vals[i];
  for (int o = 32; o > 0; o >>= 1) acc += __shfl_down(acc, o, 64);
  __shared__ float s_red[4];
  int wid = threadIdx.x >> 6, lane = threadIdx.x & 63;
  if (lane == 0) s_red[wid] = acc;
  __syncthreads();
  if (threadIdx.x == 0) outv[0] = s_red[0] + s_red[1] + s_red[2] + s_red[3];
}

extern "C" void kernel_launch(void* const* d_in, const int* in_sizes, int n_in,
                              void* d_out, int out_size, void* d_ws, size_t ws_size,
                              hipStream_t stream) {
  const float* out = (const float*)d_in[0];
  const float* target = (const float*)d_in[1];
  int nB = in_sizes[0] / (NA * (5 + NC) * SPAT);

  float* partials = (float*)d_ws;   // WTOT*nB floats

  hipLaunchKernelGGL(fused_kernel, dim3(GXB, nB), dim3(TPB), 0, stream,
                     out, target, partials);
  hipLaunchKernelGGL(reduce_kernel, dim3(1), dim3(256), 0, stream,
                     partials, WTOT * nB, (float*)d_out);
}